// Round 2
// baseline (533.951 us; speedup 1.0000x reference)
//
#include <hip/hip_runtime.h>

// WeightController: PI-style integral update + history-buffer shift.
//
// Outputs (concatenated flat in d_out, fp32):
//   [0 : 2048)                       weight_state_next
//   [2048 : 2048 + 8000*2048*5)      recording_next (history, batch, vars)
//
// R1 finding: hipMemcpyAsync D2D under graph capture took the SDMA/blit path
// at ~1.3 TB/s (522 us). The harness's own fillBuffer kernels hit 6.3 TB/s on
// this buffer, so a float4 grid-stride copy KERNEL is the fast path (m13).
// Fused: copy + controller update + last-row record in ONE launch.
//
// Memory-bound: ~655 MB total HBM traffic -> ~104 us floor at 6.3 TB/s.

#define N_BATCH     2048
#define N_HISTORY   8000
#define N_VARS      5
#define REF_V       (-0.2f)
#define K_I_V       (4.0f)
#define RATE_MAX_V  (0.01f)
#define RATE_MIN_V  (-0.02f)
#define LAMBDA_V    (1.5f)

// Shift copy: 7999 * 2048 * 5 floats = 81,909,760 floats = 20,477,440 float4
#define COPY_FLOAT4 ((size_t)(N_HISTORY - 1) * N_BATCH * N_VARS / 4)

#define BLOCK 256
#define GRID  2048   // 524,288 threads -> ~39 float4 per thread

__global__ __launch_bounds__(BLOCK) void wc_fused_kernel(
    const float* __restrict__ cv,
    const float* __restrict__ ws,
    const float* __restrict__ rec_in,
    float* __restrict__ out) {
    size_t tid    = (size_t)blockIdx.x * BLOCK + threadIdx.x;
    size_t stride = (size_t)GRID * BLOCK;

    // Bulk shift: recording[1:] -> recording_next[:7999], float4 vectorized.
    // src offset 10240 floats (40960 B), dst offset 2048 floats (8192 B):
    // both 16B-aligned; count divisible by 4.
    const float4* __restrict__ src = (const float4*)(rec_in + (size_t)N_BATCH * N_VARS);
    float4* __restrict__ dst       = (float4*)(out + N_BATCH);
    for (size_t i = tid; i < COPY_FLOAT4; i += stride) {
        dst[i] = src[i];
    }

    // Controller update + last history row (first 2048 threads only).
    // Writes out[0:2048] and the final 10240-float row — disjoint from the
    // copy's destination range, so no intra-kernel ordering needed.
    if (tid < N_BATCH) {
        int i = (int)tid;
        float c      = cv[i];
        float e      = REF_V - c;
        float to_int = K_I_V * e;
        float rl     = fminf(fmaxf(to_int, RATE_MIN_V), RATE_MAX_V);
        float wn     = fminf(fmaxf(ws[i] + rl, 0.0f), LAMBDA_V);

        out[i] = wn;  // Output 0: weight_state_next

        float* rec = out + N_BATCH
                   + (size_t)(N_HISTORY - 1) * N_BATCH * N_VARS
                   + (size_t)i * N_VARS;
        rec[0] = c;
        rec[1] = wn;
        rec[2] = to_int;
        rec[3] = rl;
        rec[4] = e;
    }
}

extern "C" void kernel_launch(void* const* d_in, const int* in_sizes, int n_in,
                              void* d_out, int out_size, void* d_ws, size_t ws_size,
                              hipStream_t stream) {
    const float* cv  = (const float*)d_in[0];   // controlled_variable (2048,)
    const float* ws  = (const float*)d_in[1];   // weight_state (2048,)
    const float* rec = (const float*)d_in[2];   // recording (8000, 2048, 5)
    float* out = (float*)d_out;

    wc_fused_kernel<<<GRID, BLOCK, 0, stream>>>(cv, ws, rec, out);
}